// Round 1
// baseline (176.618 us; speedup 1.0000x reference)
//
#include <hip/hip_runtime.h>
#include <hip/hip_bf16.h>

#define N_NODES 50000
#define N_EDGES 800000
#define IN_DIM  256
#define OUT_DIM 128

#define NBINS        256      // bins of 196 rows: 256*196 = 50176 >= 50000
#define ROWS_PER_BIN 196
#define BIN_CAP      3600     // mean 3125 + 8.5 sigma
#define EPB          2048     // edges per bin-block
#define NB_BIN       391      // ceil(800000/2048)
#define NB_GEMM      782      // ceil(3125 tiles / 4 waves per block)

typedef __bf16 bf16x8 __attribute__((ext_vector_type(8)));
typedef float  f32x4  __attribute__((ext_vector_type(4)));

// bin = floor(row/196) via magic: (r*85599)>>24, exact for r < 50176 (verified R5-R7)
__device__ __forceinline__ unsigned bin_of(unsigned r) { return (r * 85599u) >> 24; }
__device__ __forceinline__ float blo(unsigned u) { return __uint_as_float(u << 16); }
__device__ __forceinline__ float bhi(unsigned u) { return __uint_as_float(u & 0xffff0000u); }

// ---------------------------------------------------------------------------
// ws layout (bytes)
// ---------------------------------------------------------------------------
#define WT_OFF   0                      // 64 KB    : Wt bf16 [128][256]
#define SUP_OFF  65536                  // 12.8 MB  : support u32 [50000][64] planar-pair
#define BIN_OFF  12865536               // 7.37 MB  : binbuf int2[256*3600]
#define CUR_OFF  20238336               // 1 KB     : bin_cursor int[256]

// ---------------------------------------------------------------------------
// prep: Wt transpose+bf16; bin_cursor[b] = b*BIN_CAP
// ---------------------------------------------------------------------------
__global__ void k_prep(const float* __restrict__ W, __bf16* __restrict__ Wt,
                       int* __restrict__ bin_cursor) {
    int t = blockIdx.x * 256 + threadIdx.x;
    if (t < 32768) { int n = t >> 8, k = t & 255; Wt[t] = (__bf16)W[k * OUT_DIM + n]; }
    if (t < NBINS) bin_cursor[t] = t * BIN_CAP;
}

// ---------------------------------------------------------------------------
// Fused kernel.
//  blocks [0, NB_BIN): LDS-staged edge binning (verified R5-R7, unchanged).
//  blocks [NB_BIN, ..): GEMM, R9 restructure: ONE WAVE PER 16-ROW TILE,
//    no LDS, no __syncthreads, no row guard (3125*16 == 50000 exactly).
//    Each lane streams its A-fragment from global x (2x float4 per K-step,
//    bf16-convert in regs) and 8 B-fragments from L2-resident Wt, holding
//    all 8 N-tiles' accumulators.  Fragment roles and planar-pair epilogue
//    identical to the verified R7/R8 mapping (n, n+4 -> lo/hi halves).
// ---------------------------------------------------------------------------
__global__ __launch_bounds__(256) void k_fused(const float* __restrict__ x,
                                               const __bf16* __restrict__ Wt,
                                               unsigned* __restrict__ sup32,
                                               const int* __restrict__ rows,
                                               const int* __restrict__ cols,
                                               const float* __restrict__ vals,
                                               int* __restrict__ bin_cursor,
                                               int2* __restrict__ binbuf) {
    __shared__ struct {
        int2 stage[EPB];                               // 16 KB
        int  cnt[NBINS], off[NBINS], base[NBINS], cur[NBINS], s[NBINS]; // 5 KB
    } sh;
    int t = threadIdx.x;

    if (blockIdx.x < NB_BIN) {
        // ---------------- bin path (unchanged) ----------------
        long e0 = (long)blockIdx.x * EPB;
        sh.cnt[t] = 0;
        __syncthreads();

#pragma unroll
        for (int k = 0; k < EPB / 256; ++k) {
            long e = e0 + k * 256 + t;
            if (e < N_EDGES) atomicAdd(&sh.cnt[bin_of((unsigned)rows[e])], 1);
        }
        __syncthreads();

        int v = sh.cnt[t];
        sh.s[t] = v; __syncthreads();
#pragma unroll
        for (int o = 1; o < 256; o <<= 1) {
            int xv = (t >= o) ? sh.s[t - o] : 0;
            __syncthreads();
            sh.s[t] += xv;
            __syncthreads();
        }
        sh.off[t] = sh.s[t] - v;
        sh.cur[t] = sh.s[t] - v;
        sh.base[t] = atomicAdd(&bin_cursor[t], v);
        __syncthreads();

#pragma unroll
        for (int k = 0; k < EPB / 256; ++k) {
            long e = e0 + k * 256 + t;
            if (e < N_EDGES) {
                unsigned r = (unsigned)rows[e];
                unsigned c = (unsigned)cols[e];
                float    w = vals[e];
                int pos = atomicAdd(&sh.cur[bin_of(r)], 1);
                sh.stage[pos] = make_int2((int)((r << 16) | c), __float_as_int(w));
            }
        }
        __syncthreads();

        long rem = N_EDGES - e0;
        int nblk = rem < EPB ? (int)rem : EPB;
        for (int i = t; i < nblk; i += 256) {
            int2 rec = sh.stage[i];
            unsigned bn = bin_of(((unsigned)rec.x) >> 16);
            int dst = sh.base[bn] + (i - sh.off[bn]);
            if (dst < (int)(bn + 1) * BIN_CAP)
                binbuf[dst] = rec;
        }
    } else {
        // ---------------- gemm path: 1 wave = 1 tile of 16 rows ----------------
        int  gb   = blockIdx.x - NB_BIN;             // 0..781
        int  wave = t >> 6;
        int  lane = t & 63;
        int  tile = gb * 4 + wave;                   // 0..3127
        if (tile >= 3125) return;                    // no barriers below: safe
        int  m    = lane & 15;
        int  quad = lane >> 4;

        // A: lane (m,quad) streams row tile*16+m, bytes quad*32 + ks*128.
        // 3125*16 == 50000 -> every row in-bounds, no guard.
        const float*  aprow = x  + ((long)tile * 16 + m) * IN_DIM + quad * 8;
        // B: Wt[n-row][k] with n = nt*16 + m, k = quad*8 + ks*32 (verified R7 roles)
        const __bf16* wpB   = Wt + m * IN_DIM + quad * 8;

        f32x4 acc[8];
#pragma unroll
        for (int n = 0; n < 8; ++n) acc[n] = (f32x4){0, 0, 0, 0};

#pragma unroll
        for (int ks = 0; ks < 8; ++ks) {
            float4 f0 = *(const float4*)(aprow + ks * 32);
            float4 f1 = *(const float4*)(aprow + ks * 32 + 4);
            __bf16 c0 = (__bf16)f0.x, c1 = (__bf16)f0.y;
            __bf16 c2 = (__bf16)f0.z, c3 = (__bf16)f0.w;
            __bf16 c4 = (__bf16)f1.x, c5 = (__bf16)f1.y;
            __bf16 c6 = (__bf16)f1.z, c7 = (__bf16)f1.w;
            bf16x8 af = (bf16x8){c0, c1, c2, c3, c4, c5, c6, c7};
#pragma unroll
            for (int n = 0; n < 8; ++n) {
                bf16x8 bfr = *(const bf16x8*)(wpB + n * 16 * IN_DIM + ks * 32);
                acc[n] = __builtin_amdgcn_mfma_f32_16x16x32_bf16(af, bfr, acc[n], 0, 0, 0);
            }
        }

        // planar-pair epilogue (verified R7): word j = n*16+m = ch j | ch j+64
        unsigned* op = sup32 + (long)tile * 16 * 64;
#pragma unroll
        for (int r = 0; r < 4; ++r) {
#pragma unroll
            for (int n = 0; n < 4; ++n) {
                __bf16 lo = (__bf16)acc[n][r], hi = (__bf16)acc[n + 4][r];
                unsigned w = (unsigned)*(unsigned short*)&lo |
                             ((unsigned)*(unsigned short*)&hi << 16);
                op[(quad * 4 + r) * 64 + n * 16 + m] = w;
            }
        }
    }
}

// ---------------------------------------------------------------------------
// k_sg: fused per-bin counting sort + gather.
// R9 change: gather loop is now fully predicated -- no serial per-row tail,
// 8 sup-gathers always in flight (out-of-range slots re-read edge st, val=0).
// ---------------------------------------------------------------------------
__global__ __launch_bounds__(1024) void k_sg(const int* __restrict__ bin_cursor,
                                             const int2* __restrict__ binbuf,
                                             const unsigned* __restrict__ sup,
                                             const float* __restrict__ bias,
                                             float* __restrict__ out) {
    __shared__ int2 stage[BIN_CAP];                // 28.8 KB
    __shared__ int2 sorted_[BIN_CAP];              // 28.8 KB
    __shared__ int  cnt[256], off[256], cur[256], s[256];
    int b = blockIdx.x, t = threadIdx.x;
    int row0 = b * ROWS_PER_BIN;

    int n = bin_cursor[b] - b * BIN_CAP;
    n = n < 0 ? 0 : (n > BIN_CAP ? BIN_CAP : n);
    const int2* seg = binbuf + (long)b * BIN_CAP;

    if (t < 256) cnt[t] = 0;
    __syncthreads();

    for (int i = t; i < n; i += 1024) {
        int2 rec = seg[i];
        stage[i] = rec;
        atomicAdd(&cnt[(int)(((unsigned)rec.x) >> 16) - row0], 1);
    }
    __syncthreads();

    int v = 0;
    if (t < 256) { v = cnt[t]; s[t] = v; }
    __syncthreads();
#pragma unroll
    for (int o = 1; o < 256; o <<= 1) {
        int xv = 0;
        if (t < 256 && t >= o) xv = s[t - o];
        __syncthreads();
        if (t < 256) s[t] += xv;
        __syncthreads();
    }
    if (t < 256) { off[t] = s[t] - v; cur[t] = 0; }
    __syncthreads();

    for (int i = t; i < n; i += 1024) {
        int2 rec = stage[i];
        int rl = (int)(((unsigned)rec.x) >> 16) - row0;
        sorted_[off[rl] + atomicAdd(&cur[rl], 1)] = rec;
    }
    __syncthreads();

    int wave = t >> 6, lane = t & 63;
    float bb0 = bias[lane], bb1 = bias[64 + lane];

    for (int rl = wave; rl < ROWS_PER_BIN; rl += 16) {
        int row = row0 + rl;
        if (row >= N_NODES) continue;
        int st = off[rl], nd = cnt[rl];
        float a0 = 0.f, a1 = 0.f;
        for (int i = 0; i < nd; i += 8) {
            int2 e[8]; unsigned u[8]; float vv[8];
#pragma unroll
            for (int j = 0; j < 8; ++j) {
                int ok = (i + j) < nd;
                e[j]  = sorted_[ok ? st + i + j : st];
                vv[j] = ok ? __int_as_float(e[j].y) : 0.f;
            }
#pragma unroll
            for (int j = 0; j < 8; ++j)
                u[j] = sup[(long)(((unsigned)e[j].x) & 0xffffu) * 64 + lane];
#pragma unroll
            for (int j = 0; j < 8; ++j) {
                a0 += vv[j] * blo(u[j]);
                a1 += vv[j] * bhi(u[j]);
            }
        }
        out[(long)row * 128 + lane]      = a0 + bb0;
        out[(long)row * 128 + 64 + lane] = a1 + bb1;
    }
}

// ---------------------------------------------------------------------------
extern "C" void kernel_launch(void* const* d_in, const int* in_sizes, int n_in,
                              void* d_out, int out_size, void* d_ws, size_t ws_size,
                              hipStream_t stream) {
    const int*   adj_rows = (const int*)  d_in[0];
    const int*   adj_cols = (const int*)  d_in[1];
    const float* adj_vals = (const float*)d_in[2];
    const float* x        = (const float*)d_in[3];
    const float* W        = (const float*)d_in[4];
    const float* b        = (const float*)d_in[5];
    float* out = (float*)d_out;

    char* ws = (char*)d_ws;
    __bf16*   Wt         = (__bf16*)  (ws + WT_OFF);
    unsigned* sup32      = (unsigned*)(ws + SUP_OFF);
    int2*     binbuf     = (int2*)    (ws + BIN_OFF);
    int*      bin_cursor = (int*)     (ws + CUR_OFF);

    k_prep <<<128, 256, 0, stream>>>(W, Wt, bin_cursor);
    k_fused<<<NB_BIN + NB_GEMM, 256, 0, stream>>>(x, Wt, sup32,
                                                  adj_rows, adj_cols, adj_vals,
                                                  bin_cursor, binbuf);
    k_sg   <<<NBINS, 1024, 0, stream>>>(bin_cursor, binbuf, sup32, b, out);
}

// Round 2
// 176.204 us; speedup vs baseline: 1.0023x; 1.0023x over previous
//
#include <hip/hip_runtime.h>
#include <hip/hip_bf16.h>

#define N_NODES 50000
#define N_EDGES 800000
#define IN_DIM  256
#define OUT_DIM 128

#define NBINS        256      // bins of 196 rows: 256*196 = 50176 >= 50000
#define ROWS_PER_BIN 196
#define BIN_CAP      3600     // mean 3125 + 8.5 sigma
#define EPB          2048     // edges per bin-block
#define NB_BIN       391      // ceil(800000/2048)
#define NB_GEMM      782      // ceil(3125 tiles / 4 waves per block)

typedef __bf16 bf16x8 __attribute__((ext_vector_type(8)));
typedef float  f32x4  __attribute__((ext_vector_type(4)));

// bin = floor(row/196) via magic: (r*85599)>>24, exact for r < 50176 (verified R5-R7)
__device__ __forceinline__ unsigned bin_of(unsigned r) { return (r * 85599u) >> 24; }
__device__ __forceinline__ float blo(unsigned u) { return __uint_as_float(u << 16); }
__device__ __forceinline__ float bhi(unsigned u) { return __uint_as_float(u & 0xffff0000u); }

// ---------------------------------------------------------------------------
// ws layout (bytes)
// ---------------------------------------------------------------------------
#define WT_OFF   0                      // 64 KB    : Wt bf16 [128][256]
#define SUP_OFF  65536                  // 12.8 MB  : support u32 [50000][64] planar-pair
#define BIN_OFF  12865536               // 7.37 MB  : binbuf int2[256*3600]
#define CUR_OFF  20238336               // 1 KB     : bin_cursor int[256]

// ---------------------------------------------------------------------------
// prep: Wt transpose+bf16; bin_cursor[b] = b*BIN_CAP
// ---------------------------------------------------------------------------
__global__ void k_prep(const float* __restrict__ W, __bf16* __restrict__ Wt,
                       int* __restrict__ bin_cursor) {
    int t = blockIdx.x * 256 + threadIdx.x;
    if (t < 32768) { int n = t >> 8, k = t & 255; Wt[t] = (__bf16)W[k * OUT_DIM + n]; }
    if (t < NBINS) bin_cursor[t] = t * BIN_CAP;
}

// ---------------------------------------------------------------------------
// Fused kernel.
//  blocks [0, NB_BIN): R10 LEAN binning: one pass over edges (held in regs),
//    per-edge LDS rank atomic, per-bin global base atomic, direct scattered
//    write.  No prefix scan, no LDS stage, no edge re-read.  LDS 2 KB.
//  blocks [NB_BIN, ..): GEMM, R9 structure (verified): one wave per 16-row
//    tile, no LDS, no barriers, A streamed from global x, B from L2-resident
//    Wt, planar-pair epilogue (verified R7 mapping).
// ---------------------------------------------------------------------------
__global__ __launch_bounds__(256) void k_fused(const float* __restrict__ x,
                                               const __bf16* __restrict__ Wt,
                                               unsigned* __restrict__ sup32,
                                               const int* __restrict__ rows,
                                               const int* __restrict__ cols,
                                               const float* __restrict__ vals,
                                               int* __restrict__ bin_cursor,
                                               int2* __restrict__ binbuf) {
    __shared__ int s_cur[NBINS];    // per-block per-bin count / rank cursor
    __shared__ int s_base[NBINS];   // global base per bin for this block
    int t = threadIdx.x;

    if (blockIdx.x < NB_BIN) {
        // ---------------- lean bin path (R10) ----------------
        long e0 = (long)blockIdx.x * EPB;
        s_cur[t] = 0;
        __syncthreads();

        int2 rec[8];
        int  lrank[8];
        bool full = (e0 + EPB <= N_EDGES);   // true for 390 of 391 blocks

        if (full) {
#pragma unroll
            for (int k = 0; k < 8; ++k) {
                long e = e0 + k * 256 + t;
                unsigned r = (unsigned)rows[e];
                unsigned c = (unsigned)cols[e];
                float    w = vals[e];
                rec[k]   = make_int2((int)((r << 16) | c), __float_as_int(w));
                lrank[k] = atomicAdd(&s_cur[bin_of(r)], 1);
            }
        } else {
#pragma unroll
            for (int k = 0; k < 8; ++k) {
                long e = e0 + k * 256 + t;
                lrank[k] = -1;
                if (e < N_EDGES) {
                    unsigned r = (unsigned)rows[e];
                    unsigned c = (unsigned)cols[e];
                    float    w = vals[e];
                    rec[k]   = make_int2((int)((r << 16) | c), __float_as_int(w));
                    lrank[k] = atomicAdd(&s_cur[bin_of(r)], 1);
                }
            }
        }
        __syncthreads();

        s_base[t] = atomicAdd(&bin_cursor[t], s_cur[t]);
        __syncthreads();

        if (full) {
#pragma unroll
            for (int k = 0; k < 8; ++k) {
                unsigned bn = bin_of(((unsigned)rec[k].x) >> 16);
                int dst = s_base[bn] + lrank[k];
                if (dst < (int)(bn + 1) * BIN_CAP)
                    binbuf[dst] = rec[k];
            }
        } else {
#pragma unroll
            for (int k = 0; k < 8; ++k) {
                if (lrank[k] >= 0) {
                    unsigned bn = bin_of(((unsigned)rec[k].x) >> 16);
                    int dst = s_base[bn] + lrank[k];
                    if (dst < (int)(bn + 1) * BIN_CAP)
                        binbuf[dst] = rec[k];
                }
            }
        }
    } else {
        // ---------------- gemm path: 1 wave = 1 tile of 16 rows (R9) ----------------
        int  gb   = blockIdx.x - NB_BIN;             // 0..781
        int  wave = t >> 6;
        int  lane = t & 63;
        int  tile = gb * 4 + wave;                   // 0..3127
        if (tile >= 3125) return;                    // no barriers below: safe
        int  m    = lane & 15;
        int  quad = lane >> 4;

        // A: lane (m,quad) streams row tile*16+m, bytes quad*32 + ks*128.
        // 3125*16 == 50000 -> every row in-bounds, no guard.
        const float*  aprow = x  + ((long)tile * 16 + m) * IN_DIM + quad * 8;
        // B: Wt[n-row][k] with n = nt*16 + m, k = quad*8 + ks*32 (verified R7 roles)
        const __bf16* wpB   = Wt + m * IN_DIM + quad * 8;

        f32x4 acc[8];
#pragma unroll
        for (int n = 0; n < 8; ++n) acc[n] = (f32x4){0, 0, 0, 0};

#pragma unroll
        for (int ks = 0; ks < 8; ++ks) {
            float4 f0 = *(const float4*)(aprow + ks * 32);
            float4 f1 = *(const float4*)(aprow + ks * 32 + 4);
            __bf16 c0 = (__bf16)f0.x, c1 = (__bf16)f0.y;
            __bf16 c2 = (__bf16)f0.z, c3 = (__bf16)f0.w;
            __bf16 c4 = (__bf16)f1.x, c5 = (__bf16)f1.y;
            __bf16 c6 = (__bf16)f1.z, c7 = (__bf16)f1.w;
            bf16x8 af = (bf16x8){c0, c1, c2, c3, c4, c5, c6, c7};
#pragma unroll
            for (int n = 0; n < 8; ++n) {
                bf16x8 bfr = *(const bf16x8*)(wpB + n * 16 * IN_DIM + ks * 32);
                acc[n] = __builtin_amdgcn_mfma_f32_16x16x32_bf16(af, bfr, acc[n], 0, 0, 0);
            }
        }

        // planar-pair epilogue (verified R7): word j = n*16+m = ch j | ch j+64
        unsigned* op = sup32 + (long)tile * 16 * 64;
#pragma unroll
        for (int r = 0; r < 4; ++r) {
#pragma unroll
            for (int n = 0; n < 4; ++n) {
                __bf16 lo = (__bf16)acc[n][r], hi = (__bf16)acc[n + 4][r];
                unsigned w = (unsigned)*(unsigned short*)&lo |
                             ((unsigned)*(unsigned short*)&hi << 16);
                op[(quad * 4 + r) * 64 + n * 16 + m] = w;
            }
        }
    }
}

// ---------------------------------------------------------------------------
// k_sg: fused per-bin counting sort + gather (R9 predicated gather, verified).
// ---------------------------------------------------------------------------
__global__ __launch_bounds__(1024) void k_sg(const int* __restrict__ bin_cursor,
                                             const int2* __restrict__ binbuf,
                                             const unsigned* __restrict__ sup,
                                             const float* __restrict__ bias,
                                             float* __restrict__ out) {
    __shared__ int2 stage[BIN_CAP];                // 28.8 KB
    __shared__ int2 sorted_[BIN_CAP];              // 28.8 KB
    __shared__ int  cnt[256], off[256], cur[256], s[256];
    int b = blockIdx.x, t = threadIdx.x;
    int row0 = b * ROWS_PER_BIN;

    int n = bin_cursor[b] - b * BIN_CAP;
    n = n < 0 ? 0 : (n > BIN_CAP ? BIN_CAP : n);
    const int2* seg = binbuf + (long)b * BIN_CAP;

    if (t < 256) cnt[t] = 0;
    __syncthreads();

    for (int i = t; i < n; i += 1024) {
        int2 rec = seg[i];
        stage[i] = rec;
        atomicAdd(&cnt[(int)(((unsigned)rec.x) >> 16) - row0], 1);
    }
    __syncthreads();

    int v = 0;
    if (t < 256) { v = cnt[t]; s[t] = v; }
    __syncthreads();
#pragma unroll
    for (int o = 1; o < 256; o <<= 1) {
        int xv = 0;
        if (t < 256 && t >= o) xv = s[t - o];
        __syncthreads();
        if (t < 256) s[t] += xv;
        __syncthreads();
    }
    if (t < 256) { off[t] = s[t] - v; cur[t] = 0; }
    __syncthreads();

    for (int i = t; i < n; i += 1024) {
        int2 rec = stage[i];
        int rl = (int)(((unsigned)rec.x) >> 16) - row0;
        sorted_[off[rl] + atomicAdd(&cur[rl], 1)] = rec;
    }
    __syncthreads();

    int wave = t >> 6, lane = t & 63;
    float bb0 = bias[lane], bb1 = bias[64 + lane];

    for (int rl = wave; rl < ROWS_PER_BIN; rl += 16) {
        int row = row0 + rl;
        if (row >= N_NODES) continue;
        int st = off[rl], nd = cnt[rl];
        float a0 = 0.f, a1 = 0.f;
        for (int i = 0; i < nd; i += 8) {
            int2 e[8]; unsigned u[8]; float vv[8];
#pragma unroll
            for (int j = 0; j < 8; ++j) {
                int ok = (i + j) < nd;
                e[j]  = sorted_[ok ? st + i + j : st];
                vv[j] = ok ? __int_as_float(e[j].y) : 0.f;
            }
#pragma unroll
            for (int j = 0; j < 8; ++j)
                u[j] = sup[(long)(((unsigned)e[j].x) & 0xffffu) * 64 + lane];
#pragma unroll
            for (int j = 0; j < 8; ++j) {
                a0 += vv[j] * blo(u[j]);
                a1 += vv[j] * bhi(u[j]);
            }
        }
        out[(long)row * 128 + lane]      = a0 + bb0;
        out[(long)row * 128 + 64 + lane] = a1 + bb1;
    }
}

// ---------------------------------------------------------------------------
extern "C" void kernel_launch(void* const* d_in, const int* in_sizes, int n_in,
                              void* d_out, int out_size, void* d_ws, size_t ws_size,
                              hipStream_t stream) {
    const int*   adj_rows = (const int*)  d_in[0];
    const int*   adj_cols = (const int*)  d_in[1];
    const float* adj_vals = (const float*)d_in[2];
    const float* x        = (const float*)d_in[3];
    const float* W        = (const float*)d_in[4];
    const float* b        = (const float*)d_in[5];
    float* out = (float*)d_out;

    char* ws = (char*)d_ws;
    __bf16*   Wt         = (__bf16*)  (ws + WT_OFF);
    unsigned* sup32      = (unsigned*)(ws + SUP_OFF);
    int2*     binbuf     = (int2*)    (ws + BIN_OFF);
    int*      bin_cursor = (int*)     (ws + CUR_OFF);

    k_prep <<<128, 256, 0, stream>>>(W, Wt, bin_cursor);
    k_fused<<<NB_BIN + NB_GEMM, 256, 0, stream>>>(x, Wt, sup32,
                                                  adj_rows, adj_cols, adj_vals,
                                                  bin_cursor, binbuf);
    k_sg   <<<NBINS, 1024, 0, stream>>>(bin_cursor, binbuf, sup32, b, out);
}